// Round 6
// baseline (312.582 us; speedup 1.0000x reference)
//
#include <hip/hip_runtime.h>
#include <hip/hip_bf16.h>

namespace {

constexpr int T = 200;

typedef float f32x4 __attribute__((ext_vector_type(4)));
typedef short bf16x8 __attribute__((ext_vector_type(8)));

__device__ __forceinline__ short f2bf(float f) {
  __hip_bfloat16 h = __float2bfloat16(f);  // RNE; pairs fuse to v_cvt_pk_bf16_f32
  return __builtin_bit_cast(short, h);
}

template <int CTRL>
__device__ __forceinline__ float dpp_add(float x) {
  int y = __builtin_amdgcn_update_dpp(0, __float_as_int(x), CTRL, 0xF, 0xF, true);
  return x + __int_as_float(y);
}
__device__ __forceinline__ float sum16(float x) {
  x = dpp_add<0x121>(x); x = dpp_add<0x122>(x);   // row_ror 1,2,4,8
  x = dpp_add<0x124>(x); x = dpp_add<0x128>(x);
  return x;
}

__device__ __forceinline__ void async_cp16(const void* g, void* l) {
  __builtin_amdgcn_global_load_lds((__attribute__((address_space(1))) void*)g,
                                   (__attribute__((address_space(3))) void*)l, 16, 0, 0);
}

// One W fragment slot (slot<4096): d = (slot>>9)*16 + (lane&15), ks=(slot>>6)&7.
// ks<4: (Bm-C)[d][f], f=ks*32+lr*8+j ; ks>=4: Dm[d][f], f=(ks-4)*32+lr*8+j.
__device__ __forceinline__ bf16x8 w_frag(const float* __restrict__ w1, int slot) {
  int lane = slot & 63, ks = (slot >> 6) & 7, dt = slot >> 9;
  int d = dt * 16 + (lane & 15), lr = lane >> 4;
  const float* r = w1 + (size_t)d * 512;
  bf16x8 v;
  if (ks < 4) {
    int f0 = ks * 32 + lr * 8;
    f32x4 b0 = *(const f32x4*)(r + 128 + f0), b1 = *(const f32x4*)(r + 132 + f0);
    f32x4 c0 = *(const f32x4*)(r + 256 + f0), c1 = *(const f32x4*)(r + 260 + f0);
    v[0]=f2bf(b0.x-c0.x); v[1]=f2bf(b0.y-c0.y); v[2]=f2bf(b0.z-c0.z); v[3]=f2bf(b0.w-c0.w);
    v[4]=f2bf(b1.x-c1.x); v[5]=f2bf(b1.y-c1.y); v[6]=f2bf(b1.z-c1.z); v[7]=f2bf(b1.w-c1.w);
  } else {
    int f0 = (ks - 4) * 32 + lr * 8;
    f32x4 d0 = *(const f32x4*)(r + 384 + f0), d1 = *(const f32x4*)(r + 388 + f0);
    v[0]=f2bf(d0.x); v[1]=f2bf(d0.y); v[2]=f2bf(d0.z); v[3]=f2bf(d0.w);
    v[4]=f2bf(d1.x); v[5]=f2bf(d1.y); v[6]=f2bf(d1.z); v[7]=f2bf(d1.w);
  }
  return v;
}

__global__ void preW_kernel(const float* __restrict__ w1, unsigned short* __restrict__ Wp,
                            float* __restrict__ sT) {
  int idx = blockIdx.x * 256 + threadIdx.x;  // 64*256 = 16384
  int f = idx & 127, d = idx >> 7;
  sT[(size_t)f * 128 + d] = w1[(size_t)d * 512 + f] + w1[(size_t)d * 512 + 256 + f];
  if (idx < 4096) *(bf16x8*)(Wp + (size_t)idx * 8) = w_frag(w1, idx);
}

__global__ void preU_kernel(const float* __restrict__ qg, const float* __restrict__ sT,
                            const float* __restrict__ b1g, float* __restrict__ uall) {
  __shared__ float qs[128];
  int b = blockIdx.x, d = threadIdx.x;
  qs[d] = qg[(size_t)b * 128 + d];
  __syncthreads();
  float acc = b1g[d];
  #pragma unroll 16
  for (int f = 0; f < 128; ++f) acc += qs[f] * sT[(size_t)f * 128 + d];
  uall[(size_t)b * 128 + d] = acc;
}

__global__ __launch_bounds__(512, 2) void din_kernel(
    const float* __restrict__ qg, const float* __restrict__ keysg,
    const void* __restrict__ maskg, const float* __restrict__ w1g,
    const float* __restrict__ b1g, const float* __restrict__ pag,
    const float* __restrict__ w2g, const float* __restrict__ b2g,
    const unsigned short* __restrict__ Wp, const float* __restrict__ uall,
    int mode, float* __restrict__ outg) {
  __shared__ __align__(16) unsigned short Wlds[32768];  // 64 KB, frag-major

  const int tid  = threadIdx.x;
  const int wid  = tid >> 6;              // 0..7
  const int lane = tid & 63;
  const int lrow = lane >> 4;             // 0..3
  const int lcol = lane & 15;
  const int b    = (blockIdx.x << 3) + wid;  // wave owns batch b outright

  const float* qb    = qg + (size_t)b * 128;
  const float* keysB = keysg + (size_t)b * T * 128;

  // ---- mask dtype detector (wave-uniform, no barrier) ----
  int mcode;
  {
    unsigned v = ((const unsigned*)maskg)[lane];
    unsigned c0 = v & 255u, c1 = (v >> 8) & 255u, c2 = (v >> 16) & 255u, c3 = v >> 24;
    bool weird = (c0 == 0x80u) | (c0 == 0x3Fu) | (c1 == 0x80u) | (c1 == 0x3Fu) |
                 (c2 == 0x80u) | (c2 == 0x3Fu) | (c3 == 0x80u) | (c3 == 0x3Fu);
    bool nz = (v & 0xFFFFFF00u) != 0u;
    unsigned long long bw = __ballot(weird);
    unsigned long long bn = __ballot(nz);
    mcode = bw ? 2 : (bn ? 1 : 0);  // 2=f32, 1=byte, 0=int32
  }

  const float pa  = pag[0];
  const float b2v = b2g[0];

  // ---- K tiles 0,1 prefetch (A-frag: lane row=lcol, f=ks*32+lrow*8+j) ----
  f32x4 ka0[4], ka1[4], kb0[4], kb1[4];
  #define LOADK(K0, K1, TILE)                                        \
    do {                                                             \
      int trow_ = (TILE) * 16 + lcol;                                \
      int trc_ = trow_ < T ? trow_ : T - 1;                          \
      const float* kr_ = keysB + (size_t)trc_ * 128 + lrow * 8;      \
      _Pragma("unroll")                                              \
      for (int ks = 0; ks < 4; ++ks) {                               \
        K0[ks] = *(const f32x4*)(kr_ + ks * 32);                     \
        K1[ks] = *(const f32x4*)(kr_ + ks * 32 + 4);                 \
      }                                                              \
    } while (0)
  LOADK(ka0, ka1, 0);
  LOADK(kb0, kb1, 1);

  // ---- q fragments (match K f-slots) ----
  f32x4 qf0[4], qf1[4];
  #pragma unroll
  for (int ks = 0; ks < 4; ++ks) {
    qf0[ks] = *(const f32x4*)(qb + ks * 32 + lrow * 8);
    qf1[ks] = *(const f32x4*)(qb + ks * 32 + lrow * 8 + 4);
  }

  // ---- stage W (shared, b-independent): linear, conflict-free frag table ----
  if (mode >= 1) {
    #pragma unroll
    for (int i = 0; i < 8; ++i)
      async_cp16((const char*)Wp + ((size_t)tid + i * 512) * 16,
                 (char*)Wlds + ((size_t)tid + i * 512) * 16);
  } else {
    #pragma unroll
    for (int i = 0; i < 8; ++i) {
      int slot = tid + i * 512;
      *(bf16x8*)((char*)Wlds + (size_t)slot * 16) = w_frag(w1g, slot);
    }
  }

  // ---- per-wave u_d[8]: u[d] at d = dt*16+lcol ----
  float u_d[8];
  if (mode == 2) {
    #pragma unroll
    for (int dt = 0; dt < 8; ++dt) u_d[dt] = uall[(size_t)b * 128 + dt * 16 + lcol];
  } else {
    int d0 = lane * 2;
    float ua = b1g[d0], ub = b1g[d0 + 1];
    const float* r0 = w1g + (size_t)d0 * 512;
    const float* r1 = r0 + 512;
    #pragma unroll 8
    for (int f = 0; f < 128; f += 4) {
      f32x4 qv = *(const f32x4*)(qb + f);
      f32x4 a0 = *(const f32x4*)(r0 + f), c0 = *(const f32x4*)(r0 + 256 + f);
      f32x4 a1 = *(const f32x4*)(r1 + f), c1 = *(const f32x4*)(r1 + 256 + f);
      ua += qv.x*(a0.x+c0.x) + qv.y*(a0.y+c0.y) + qv.z*(a0.z+c0.z) + qv.w*(a0.w+c0.w);
      ub += qv.x*(a1.x+c1.x) + qv.y*(a1.y+c1.y) + qv.z*(a1.z+c1.z) + qv.w*(a1.w+c1.w);
    }
    #pragma unroll
    for (int dt = 0; dt < 8; ++dt) {
      int d = dt * 16 + lcol;
      float ta = __shfl(ua, d >> 1, 64);
      float tb = __shfl(ub, d >> 1, 64);
      u_d[dt] = (d & 1) ? tb : ta;
    }
  }

  float w2d[8];
  #pragma unroll
  for (int dt = 0; dt < 8; ++dt) w2d[dt] = w2g[dt * 16 + lcol];

  __syncthreads();  // THE barrier: W staged (drains async); waves free-run after

  float m_w = -1e9f, den_w = 0.f;
  float accpv[32];
  #pragma unroll
  for (int i = 0; i < 32; ++i) accpv[i] = 0.f;

  #define BODY(TILE, K0, K1, PF)                                              \
    do {                                                                      \
      const int tile_ = (TILE);                                               \
      bf16x8 af[8];                                                           \
      _Pragma("unroll")                                                       \
      for (int ks = 0; ks < 4; ++ks) {                                        \
        af[ks][0]=f2bf(K0[ks].x); af[ks][1]=f2bf(K0[ks].y);                   \
        af[ks][2]=f2bf(K0[ks].z); af[ks][3]=f2bf(K0[ks].w);                   \
        af[ks][4]=f2bf(K1[ks].x); af[ks][5]=f2bf(K1[ks].y);                   \
        af[ks][6]=f2bf(K1[ks].z); af[ks][7]=f2bf(K1[ks].w);                   \
        af[ks+4][0]=f2bf(K0[ks].x*qf0[ks].x); af[ks+4][1]=f2bf(K0[ks].y*qf0[ks].y); \
        af[ks+4][2]=f2bf(K0[ks].z*qf0[ks].z); af[ks+4][3]=f2bf(K0[ks].w*qf0[ks].w); \
        af[ks+4][4]=f2bf(K1[ks].x*qf1[ks].x); af[ks+4][5]=f2bf(K1[ks].y*qf1[ks].y); \
        af[ks+4][6]=f2bf(K1[ks].z*qf1[ks].z); af[ks+4][7]=f2bf(K1[ks].w*qf1[ks].w); \
      }                                                                       \
      float sj[4] = {0.f, 0.f, 0.f, 0.f};                                     \
      _Pragma("unroll")                                                       \
      for (int dt = 0; dt < 8; ++dt) {                                        \
        f32x4 acc = {u_d[dt], u_d[dt], u_d[dt], u_d[dt]};                     \
        _Pragma("unroll")                                                     \
        for (int ks = 0; ks < 8; ++ks) {                                      \
          bf16x8 bfv = *(const bf16x8*)((const char*)Wlds +                   \
                                        (((dt * 8 + ks) * 64 + lane) * 16));  \
          acc = __builtin_amdgcn_mfma_f32_16x16x32_bf16(af[ks], bfv, acc, 0, 0, 0); \
        }                                                                     \
        _Pragma("unroll")                                                     \
        for (int j = 0; j < 4; ++j) {                                         \
          float h = acc[j];                                                   \
          h = (h >= 0.f) ? h : pa * h;                                        \
          sj[j] += h * w2d[dt];                                               \
        }                                                                     \
      }                                                                       \
      _Pragma("unroll")                                                       \
      for (int j = 0; j < 4; ++j) sj[j] = sum16(sj[j]);                       \
      float mt = -1e30f;                                                      \
      _Pragma("unroll")                                                       \
      for (int j = 0; j < 4; ++j) {                                           \
        int t_ = tile_ * 16 + lrow * 4 + j;                                   \
        bool valid = (t_ < T);                                                \
        if (valid) {                                                          \
          size_t mi = (size_t)b * T + t_;                                     \
          if (mcode == 0)      valid = ((const int*)maskg)[mi] != 0;          \
          else if (mcode == 1) valid = ((const unsigned char*)maskg)[mi] != 0;\
          else                 valid = ((const float*)maskg)[mi] != 0.f;      \
        }                                                                     \
        sj[j] = valid ? (sj[j] + b2v) : -1e30f;                               \
        mt = fmaxf(mt, sj[j]);                                                \
      }                                                                       \
      mt = fmaxf(mt, __shfl_xor(mt, 16));                                     \
      mt = fmaxf(mt, __shfl_xor(mt, 32));                                     \
      if (mt > m_w) {  /* exact defer-max */                                  \
        float sc = __expf(m_w - mt);                                          \
        den_w *= sc;                                                          \
        _Pragma("unroll")                                                     \
        for (int i = 0; i < 32; ++i) accpv[i] *= sc;                          \
        m_w = mt;                                                             \
      }                                                                       \
      float wj[4], dsum = 0.f;                                                \
      _Pragma("unroll")                                                       \
      for (int j = 0; j < 4; ++j) { wj[j] = __expf(sj[j] - m_w); dsum += wj[j]; } \
      dsum += __shfl_xor(dsum, 16);                                           \
      dsum += __shfl_xor(dsum, 32);                                           \
      den_w += dsum;                                                          \
      float tmp = (lcol & 2) ? ((lcol & 1) ? wj[3] : wj[2])                   \
                             : ((lcol & 1) ? wj[1] : wj[0]);                  \
      float wtr = __shfl(tmp, ((lcol >> 2) << 4) | (lcol & 3), 64);           \
      _Pragma("unroll")                                                       \
      for (int ks = 0; ks < 4; ++ks) {                                        \
        accpv[ks*8+0] += wtr * K0[ks].x; accpv[ks*8+1] += wtr * K0[ks].y;     \
        accpv[ks*8+2] += wtr * K0[ks].z; accpv[ks*8+3] += wtr * K0[ks].w;     \
        accpv[ks*8+4] += wtr * K1[ks].x; accpv[ks*8+5] += wtr * K1[ks].y;     \
        accpv[ks*8+6] += wtr * K1[ks].z; accpv[ks*8+7] += wtr * K1[ks].w;     \
      }                                                                       \
      if ((PF) >= 0) LOADK(K0, K1, (PF));                                     \
    } while (0)

  // 13 tiles: even/odd buffer rotation, prefetch distance = one full body
  for (int t = 0; t < 12; t += 2) {
    BODY(t,     ka0, ka1, t + 2);
    BODY(t + 1, kb0, kb1, (t + 3 <= 12) ? t + 3 : -1);
  }
  BODY(12, ka0, ka1, -1);

  // ---- fold K-rows (lcol dir) via DPP; lcol==0 lanes hold 32 f-slots each ----
  #pragma unroll
  for (int i = 0; i < 32; ++i) accpv[i] = sum16(accpv[i]);
  if (lcol == 0) {
    float inv = (den_w > 0.f) ? 1.0f / den_w : 0.f;
    float* ob = outg + (size_t)b * 128;
    #pragma unroll
    for (int ks = 0; ks < 4; ++ks) {
      f32x4 a = {accpv[ks*8+0]*inv, accpv[ks*8+1]*inv, accpv[ks*8+2]*inv, accpv[ks*8+3]*inv};
      f32x4 c = {accpv[ks*8+4]*inv, accpv[ks*8+5]*inv, accpv[ks*8+6]*inv, accpv[ks*8+7]*inv};
      *(f32x4*)(ob + ks * 32 + lrow * 8)     = a;
      *(f32x4*)(ob + ks * 32 + lrow * 8 + 4) = c;
    }
  }
  #undef BODY
  #undef LOADK
}

}  // namespace

extern "C" void kernel_launch(void* const* d_in, const int* in_sizes, int n_in,
                              void* d_out, int out_size, void* d_ws, size_t ws_size,
                              hipStream_t stream) {
  (void)in_sizes; (void)n_in; (void)out_size;
  const float* q    = (const float*)d_in[0];
  const float* keys = (const float*)d_in[1];
  const void*  mask = d_in[2];
  const float* w1   = (const float*)d_in[3];
  const float* b1   = (const float*)d_in[4];
  const float* pa   = (const float*)d_in[5];
  const float* w2   = (const float*)d_in[6];
  const float* b2   = (const float*)d_in[7];
  float* out = (float*)d_out;

  unsigned short* Wp = (unsigned short*)d_ws;                  // 64 KB bf16 frag table
  float* sT   = (float*)((char*)d_ws + 65536);                 // 64 KB (A+C)^T f32
  float* uall = (float*)((char*)d_ws + 131072);                // 1 MB u[B][128]
  int mode = 0;
  if (ws_size >= (size_t)131072 + (size_t)2048 * 128 * 4) mode = 2;
  else if (ws_size >= (size_t)131072)                     mode = 1;

  if (mode >= 1) preW_kernel<<<64, 256, 0, stream>>>(w1, Wp, sT);
  if (mode == 2) preU_kernel<<<2048, 128, 0, stream>>>(q, sT, b1, uall);
  din_kernel<<<256, 512, 0, stream>>>(q, keys, mask, w1, b1, pa, w2, b2,
                                      Wp, uall, mode, out);
}